// Round 14
// baseline (390.019 us; speedup 1.0000x reference)
//
#include <hip/hip_runtime.h>
#include <hip/hip_bf16.h>
#include <math.h>

// ---------------- Problem constants ----------------
constexpr int B_   = 2;
constexpr int T_   = 2048;
constexpr int DM   = 2048;   // d_model
constexpr int H_   = 16;
constexpr int DH   = 128;    // d_head
constexpr int DC   = 512;    // d_c
constexpr int DR   = 64;     // d_rope
constexpr int DQK  = DH + DR;        // 192
constexpr int BT   = B_ * T_;        // 4096
constexpr int ZBH  = B_ * H_;        // 32

typedef __bf16 bf16x8 __attribute__((ext_vector_type(8)));
typedef float  f32x4  __attribute__((ext_vector_type(4)));
typedef unsigned int u32x2 __attribute__((ext_vector_type(2)));
typedef unsigned short u16x4 __attribute__((ext_vector_type(4)));

__device__ __forceinline__ unsigned pk2(float a, float b) {
  __hip_bfloat162 t = __float22bfloat162_rn(make_float2(a, b));
  return *reinterpret_cast<unsigned*>(&t);
}
__device__ __forceinline__ unsigned short bfbits(float v) {
  __hip_bfloat16 t = __float2bfloat16(v);
  return *reinterpret_cast<unsigned short*>(&t);
}

#define WAITVM(N)   asm volatile("s_waitcnt vmcnt(" #N ")" ::: "memory")
#define BARSB() do { __builtin_amdgcn_s_barrier(); __builtin_amdgcn_sched_barrier(0); } while (0)
#define AS1 __attribute__((address_space(1)))
#define AS3 __attribute__((address_space(3)))

// ---------------- prep: casts + weight transposes + pad + rope tables ------
__global__ __launch_bounds__(256)
void prep(const float* __restrict__ query, const float* __restrict__ key,
          const float* __restrict__ W_Q, const float* __restrict__ W_QR,
          const float* __restrict__ W_DKV, const float* __restrict__ W_KR,
          const float* __restrict__ W_UK, const float* __restrict__ W_UV,
          const float* __restrict__ W_O,
          __hip_bfloat16* __restrict__ qB, __hip_bfloat16* __restrict__ kB,
          __hip_bfloat16* __restrict__ Wtqall, __hip_bfloat16* __restrict__ Wtkall,
          __hip_bfloat16* __restrict__ Wtkvup, __hip_bfloat16* __restrict__ WtO,
          float* __restrict__ ctab, float* __restrict__ stab) {
  __shared__ float tile[32][33];
  const int blk = blockIdx.x;
  const int tid = threadIdx.x;

  if (blk < 4096) {                      // casts: 4096 floats per block
    const float* src = (blk < 2048) ? query : key;
    __hip_bfloat16* dst = (blk < 2048) ? qB : kB;
    const long base = (long)(blk & 2047) * 4096;
    #pragma unroll
    for (int c = 0; c < 4; ++c) {
      const long off = base + c * 1024 + tid * 4;
      float4 f = *(const float4*)(src + off);
      u16x4 pk;
      pk[0] = bfbits(f.x); pk[1] = bfbits(f.y); pk[2] = bfbits(f.z); pk[3] = bfbits(f.w);
      *(u16x4*)(dst + off) = pk;
    }
    return;
  }

  int b = blk - 4096;
  const float* W = nullptr; __hip_bfloat16* Wt = nullptr; int K = 2048, N = 2048;
  if (b < 4096)               { W = W_Q;   Wt = Wtqall; }
  else if ((b -= 4096) < 2048){ W = W_QR;  Wt = Wtqall + (size_t)2048 * 2048; N = 1024; }
  else if ((b -= 2048) < 1024){ W = W_DKV; Wt = Wtkall; N = 512; }
  else if ((b -= 1024) < 128) { W = W_KR;  Wt = Wtkall + (size_t)512 * 2048; N = 64; }
  else if ((b -= 128) < 1024) { W = W_UK;  Wt = Wtkvup; K = 512; }
  else if ((b -= 1024) < 1024){ W = W_UV;  Wt = Wtkvup + (size_t)2048 * 512; K = 512; }
  else if ((b -= 1024) < 4096){ W = W_O;   Wt = WtO; }
  else if ((b -= 4096) < 192) {           // zero-pad Wtkall rows 576..767
    float4 z = {0.f, 0.f, 0.f, 0.f};
    *(float4*)((char*)(Wtkall + (size_t)(576 + b) * 2048) + tid * 16) = z;
    return;
  }
  else {                                  // rope tables
    b -= 192;
    const int i = b * 256 + tid;
    const int t = i >> 5, j = i & 31;
    double inv = pow(10000.0, -(double)j / 32.0);
    double ang = (double)t * inv;
    ctab[i] = (float)cos(ang);
    stab[i] = (float)sin(ang);
    return;
  }
  const int nx = N >> 5;
  const int n0 = (b % nx) << 5, k0 = (b / nx) << 5;
  const int tx = tid & 31, ty = tid >> 5;
  for (int i = ty; i < 32; i += 8)
    tile[i][tx] = W[(long)(k0 + i) * N + n0 + tx];
  __syncthreads();
  for (int i = ty; i < 32; i += 8)
    Wt[(long)(n0 + i) * K + k0 + tx] = __float2bfloat16(tile[tx][i]);
}

// ---------------- 4-wave 128x256 GEMM core (per-wave 128x64, LDS-lean) -----
template <int MODE>
__device__ __forceinline__
void gemm4w_core(const __hip_bfloat16* __restrict__ A, const __hip_bfloat16* __restrict__ Bt,
                 void* __restrict__ C0, void* __restrict__ C1,
                 int N, int K, int lda,
                 const float* __restrict__ ctab, const float* __restrict__ stab,
                 int bid, int nwg, char* lds) {
  const int gnx = N >> 8;
  const int cpx = nwg >> 3;                      // nwg % 8 == 0 for all callers
  const int swz = (bid & 7) * cpx + (bid >> 3);  // bijective XCD chunking
  const int n0 = (swz % gnx) << 8;
  const int m0 = (swz / gnx) << 7;

  const int tid  = threadIdx.x;
  const int wc   = tid >> 6;       // wave = N quarter (0..3)
  const int lane = tid & 63;
  const int rr   = lane & 15;
  const int kq   = lane >> 4;

  const int cs16 = (((tid & 3) ^ ((tid >> 3) & 3)) << 4);
  const int srow = tid >> 2;

  auto stage = [&](int buf, int k0) {            // 6 global_load_lds / thread
    char* base = lds + buf * 24576;
    #pragma unroll
    for (int c = 0; c < 2; ++c) {
      const char* src = (const char*)A + (((long)(m0 + c * 64 + srow)) * lda + k0) * 2 + cs16;
      __builtin_amdgcn_global_load_lds((const AS1 void*)src,
          (AS3 void*)(base + c * 4096 + tid * 16), 16, 0, 0);
    }
    #pragma unroll
    for (int c = 0; c < 4; ++c) {
      const char* src = (const char*)Bt + (((long)(n0 + c * 64 + srow)) * K + k0) * 2 + cs16;
      __builtin_amdgcn_global_load_lds((const AS1 void*)src,
          (AS3 void*)(base + 8192 + c * 4096 + tid * 16), 16, 0, 0);
    }
  };

  const int g16 = ((kq ^ ((rr >> 1) & 3)) << 4);
  const int aoff0 = rr * 64 + g16;                        // + mf*1024
  const int boff0 = 8192 + (wc * 64 + rr) * 64 + g16;     // + nf*1024

  f32x4 acc[8][4] = {};

  auto phase = [&](int buf) {
    char* base = lds + buf * 24576;
    bf16x8 a[8], b[4];
    #pragma unroll
    for (int mf = 0; mf < 8; ++mf) a[mf] = *(const bf16x8*)(base + aoff0 + mf * 1024);
    #pragma unroll
    for (int nf = 0; nf < 4; ++nf) b[nf] = *(const bf16x8*)(base + boff0 + nf * 1024);
    __builtin_amdgcn_s_setprio(1);
    #pragma unroll
    for (int mf = 0; mf < 8; ++mf)
      #pragma unroll
      for (int nf = 0; nf < 4; ++nf)
        acc[mf][nf] = __builtin_amdgcn_mfma_f32_16x16x32_bf16(a[mf], b[nf], acc[mf][nf], 0, 0, 0);
    __builtin_amdgcn_s_setprio(0);
  };

  const int NT = K >> 5;                         // K-32 tiles
  stage(0, 0); stage(1, 32);                     // 12 loads in flight
  int cur = 0;
  for (int t = 0; t < NT; ++t) {
    if (t + 1 < NT) WAITVM(6); else WAITVM(0);
    BARSB();
    if (t + 2 < NT) {
      const int b2 = (cur + 2 >= 3) ? cur - 1 : cur + 2;
      stage(b2, (t + 2) << 5);
    }
    phase(cur);
    cur = (cur + 1 >= 3) ? 0 : cur + 1;
  }

  // epilogue: row = m0 + mf*16 + kq*4 + j, col = n0 + wc*64 + nf*16 + rr
  #pragma unroll
  for (int mf = 0; mf < 8; ++mf) {
    #pragma unroll
    for (int nf = 0; nf < 4; ++nf) {
      const int col = n0 + wc * 64 + nf * 16 + rr;
      const int rbase = m0 + mf * 16 + kq * 4;
      if constexpr (MODE == 1) {
        float* C = (float*)C0;
        #pragma unroll
        for (int j = 0; j < 4; ++j)
          __builtin_nontemporal_store(acc[mf][nf][j], &C[(long)(rbase + j) * N + col]);
      } else if constexpr (MODE == 2) {
        __hip_bfloat16* qall = (__hip_bfloat16*)C0;
        if (col < 2048) {
          #pragma unroll
          for (int j = 0; j < 4; ++j)
            qall[(long)(rbase + j) * 3072 + col] = __float2bfloat16(acc[mf][nf][j]);
        } else {
          const int dr = (col - 2048) & 63;
          const int jj = dr >> 1;
          #pragma unroll
          for (int j = 0; j < 4; ++j) {
            const int row = rbase + j;
            const int t = row & (T_ - 1);
            const float c = ctab[t * 32 + jj], s = stab[t * 32 + jj];
            const float v  = acc[mf][nf][j];
            const float pv = __shfl_xor(v, 1);
            const float res = (dr & 1) ? (pv * s + v * c) : (v * c - pv * s);
            qall[(long)row * 3072 + col] = __float2bfloat16(res);
          }
        }
      } else if constexpr (MODE == 3) {
        __hip_bfloat16* ckv = (__hip_bfloat16*)C0;
        __hip_bfloat16* krp = (__hip_bfloat16*)C1;
        if (col < 512) {
          #pragma unroll
          for (int j = 0; j < 4; ++j)
            ckv[(long)(rbase + j) * 512 + col] = __float2bfloat16(acc[mf][nf][j]);
        } else if (col < 576) {
          const int dr = col - 512;
          const int jj = dr >> 1;
          #pragma unroll
          for (int j = 0; j < 4; ++j) {
            const int row = rbase + j;
            const int t = row & (T_ - 1);
            const float c = ctab[t * 32 + jj], s = stab[t * 32 + jj];
            const float v  = acc[mf][nf][j];
            const float pv = __shfl_xor(v, 1);
            const float res = (dr & 1) ? (pv * s + v * c) : (v * c - pv * s);
            krp[(long)row * 64 + dr] = __float2bfloat16(res);
          }
        }            // cols >= 576: zero-padded, discard
      } else if constexpr (MODE == 4) {
        __hip_bfloat16* knope = (__hip_bfloat16*)C0;
        __hip_bfloat16* vT    = (__hip_bfloat16*)C1;
        if (col < 2048) {
          #pragma unroll
          for (int j = 0; j < 4; ++j)
            knope[(long)(rbase + j) * 2048 + col] = __float2bfloat16(acc[mf][nf][j]);
        } else {
          const int h = (col - 2048) >> 7, d = (col - 2048) & 127;
          const int z = (rbase >> 11) * 16 + h;
          const int t0 = rbase & (T_ - 1);
          u16x4 pk;
          #pragma unroll
          for (int j = 0; j < 4; ++j) pk[j] = bfbits(acc[mf][nf][j]);
          *(u16x4*)((__hip_bfloat16*)vT + ((long)z * DH + d) * T_ + t0) = pk;
        }
      }
    }
  }
}

template <int MODE>
__global__ __launch_bounds__(256, 2)
void gemm_4w(const __hip_bfloat16* __restrict__ A, const __hip_bfloat16* __restrict__ Bt,
             void* __restrict__ C0, void* __restrict__ C1,
             int M, int N, int K, int lda,
             const float* __restrict__ ctab, const float* __restrict__ stab) {
  __shared__ __align__(16) char lds[73728];
  gemm4w_core<MODE>(A, Bt, C0, C1, N, K, lda, ctab, stab,
                    blockIdx.x, (M >> 7) * (N >> 8), lds);
}

// ---- merged q_all + k_all projection: independent GEMMs, one dispatch -----
__global__ __launch_bounds__(256, 2)
void proj_qk(const __hip_bfloat16* __restrict__ qB, const __hip_bfloat16* __restrict__ kB,
             const __hip_bfloat16* __restrict__ Wtqall, const __hip_bfloat16* __restrict__ Wtkall,
             __hip_bfloat16* __restrict__ q_all, __hip_bfloat16* __restrict__ ckv,
             __hip_bfloat16* __restrict__ kroper,
             const float* __restrict__ ctab, const float* __restrict__ stab) {
  __shared__ __align__(16) char lds[73728];
  if (blockIdx.x < 384)
    gemm4w_core<2>(qB, Wtqall, q_all, nullptr, 3072, 2048, 2048, ctab, stab,
                   blockIdx.x, 384, lds);
  else
    gemm4w_core<3>(kB, Wtkall, ckv, kroper, 768, 2048, 2048, ctab, stab,
                   blockIdx.x - 384, 96, lds);
}

// ---------------- 8-wave 128x256 GEMM (out-GEMM: 8 waves/CU at grid 256) ---
__global__ __launch_bounds__(512, 2)
void gemm_8w_out(const __hip_bfloat16* __restrict__ A, const __hip_bfloat16* __restrict__ Bt,
                 float* __restrict__ C, int M, int N, int K, int lda) {
  const int gnx = N >> 8;
  const int nwg = (M >> 7) * gnx;
  const int cpx = nwg >> 3;
  const int bid = blockIdx.x;
  const int swz = (bid & 7) * cpx + (bid >> 3);
  const int n0 = (swz % gnx) << 8;
  const int m0 = (swz / gnx) << 7;

  __shared__ __align__(16) char lds[147456];

  const int tid  = threadIdx.x;
  const int wv   = tid >> 6;
  const int lane = tid & 63;
  const int wr   = wv >> 2;
  const int wc   = wv & 3;
  const int rr   = lane & 15;
  const int kq   = lane >> 4;

  const int cs16 = (((tid & 3) ^ ((tid >> 3) & 3)) << 4);
  const long arow  = m0 + (tid >> 2);
  const long brow0 = n0 + (tid >> 2);
  const long brow1 = n0 + 128 + (tid >> 2);

  auto stage = [&](int buf, int kh, int k0) {
    char* base = lds + buf * 49152 + kh * 24576;
    const long kk = (long)k0 + kh * 32;
    const char* asrc = (const char*)A + (arow * lda + kk) * 2 + cs16;
    __builtin_amdgcn_global_load_lds((const AS1 void*)asrc,
                                     (AS3 void*)(base + tid * 16), 16, 0, 0);
    const char* bsrc0 = (const char*)Bt + (brow0 * K + kk) * 2 + cs16;
    __builtin_amdgcn_global_load_lds((const AS1 void*)bsrc0,
                                     (AS3 void*)(base + 8192 + tid * 16), 16, 0, 0);
    const char* bsrc1 = (const char*)Bt + (brow1 * K + kk) * 2 + cs16;
    __builtin_amdgcn_global_load_lds((const AS1 void*)bsrc1,
                                     (AS3 void*)(base + 16384 + tid * 16), 16, 0, 0);
  };

  const int g16 = ((kq ^ ((rr >> 1) & 3)) << 4);
  const int aoff0 = (wr * 64 + rr) * 64 + g16;
  const int boff0 = 8192 + (wc * 64 + rr) * 64 + g16;

  f32x4 acc[4][4] = {};

  auto phase = [&](int buf, int kh) {
    char* base = lds + buf * 49152 + kh * 24576;
    bf16x8 a[4], b[4];
    #pragma unroll
    for (int mf = 0; mf < 4; ++mf) a[mf] = *(const bf16x8*)(base + aoff0 + mf * 1024);
    #pragma unroll
    for (int nf = 0; nf < 4; ++nf) b[nf] = *(const bf16x8*)(base + boff0 + nf * 1024);
    __builtin_amdgcn_s_setprio(1);
    #pragma unroll
    for (int mf = 0; mf < 4; ++mf)
      #pragma unroll
      for (int nf = 0; nf < 4; ++nf)
        acc[mf][nf] = __builtin_amdgcn_mfma_f32_16x16x32_bf16(a[mf], b[nf], acc[mf][nf], 0, 0, 0);
    __builtin_amdgcn_s_setprio(0);
  };

  const int NT = K >> 6;
  stage(0, 0, 0); stage(0, 1, 0);
  stage(1, 0, 64); stage(1, 1, 64);
  int cur = 0;
  for (int t = 0; t < NT; ++t) {
    const int b2 = (cur + 2 >= 3) ? cur - 1 : cur + 2;
    if (t + 2 < NT) {
      const int k2 = (t + 2) << 6;
      WAITVM(9);  BARSB();
      stage(b2, 0, k2);
      phase(cur, 0);
      WAITVM(9);  BARSB();
      stage(b2, 1, k2);
      phase(cur, 1);
    } else if (t + 2 == NT) {
      WAITVM(9);  BARSB();  phase(cur, 0);
      WAITVM(6);  BARSB();  phase(cur, 1);
    } else {
      WAITVM(3);  BARSB();  phase(cur, 0);
      WAITVM(0);  BARSB();  phase(cur, 1);
    }
    cur = (cur + 1 >= 3) ? 0 : cur + 1;
  }

  #pragma unroll
  for (int mf = 0; mf < 4; ++mf) {
    #pragma unroll
    for (int nf = 0; nf < 4; ++nf) {
      const int col = n0 + wc * 64 + nf * 16 + rr;
      const int rbase = m0 + wr * 64 + mf * 16 + kq * 4;
      #pragma unroll
      for (int j = 0; j < 4; ++j)
        __builtin_nontemporal_store(acc[mf][nf][j], &C[(long)(rbase + j) * N + col]);
    }
  }
}

// ---------------- Fused attention: scores + softmax + PV -------------------
// 80 KB LDS -> 2 blocks/CU. Pass 1: 3 K-buffers, stage-after-barrier.
// Pass 2: K dbuf + single V + P; P-stores issued AFTER B2/stage_v so the
// per-tile wait is WAITVM(4) (stores ride the queue, never drained in-loop).
__global__ __launch_bounds__(512, 4)
void fused_attn(const __hip_bfloat16* __restrict__ q_all,
                const __hip_bfloat16* __restrict__ knope,
                const __hip_bfloat16* __restrict__ kroper,
                const __hip_bfloat16* __restrict__ vTg,
                float* __restrict__ patt,
                __hip_bfloat16* __restrict__ xplain) {
  constexpr int KT = 64;
  constexpr int NKT = T_ / KT;           // 32
  const int bid = blockIdx.x;
  const int swz = (bid & 7) * 64 + (bid >> 3);
  const int z  = swz >> 4;
  const int q0 = (swz & 15) << 7;
  const int b  = z >> 4, h = z & 15;
  const int tid  = threadIdx.x;
  const int wv   = tid >> 6;
  const int lane = tid & 63;
  const int rr   = lane & 15;
  const int kq   = lane >> 4;
  const float scl = 0.0721687836487032f; // 1/sqrt(192)

  // map: pass1 K bufs @0/24576/49152 ; pass2 K0@0 K1@24576 V@49152 P@65536
  __shared__ __align__(16) char smem[81920];
  char* const lV = smem + 49152;
  char* const lP = smem + 65536;

  const long qrow = (long)(b * T_) + q0 + wv * 16 + rr;
  const __hip_bfloat16* qn = q_all + qrow * 3072 + h * 128;
  const __hip_bfloat16* qr = q_all + qrow * 3072 + 2048 + h * 64;
  bf16x8 qa[6];
  #pragma unroll
  for (int kc = 0; kc < 4; ++kc) qa[kc] = *(const bf16x8*)(qn + kc * 32 + kq * 8);
  #pragma unroll
  for (int kc = 0; kc < 2; ++kc) qa[4 + kc] = *(const bf16x8*)(qr + kc * 32 + kq * 8);

  auto stage_k = [&](char* dst, int kt0) {       // 3 VMEM loads / thread
    #pragma unroll
    for (int it = 0; it < 3; ++it) {
      const int off = it * 8192 + wv * 1024;
      const int lb  = off + lane * 16;
      const int row = lb / 384, cb = lb % 384;
      const int scb = cb ^ ((row & 7) << 4);
      const long trow = (long)(b * T_) + kt0 + row;
      const char* src = (scb < 256)
          ? (const char*)knope + trow * 4096 + h * 256 + scb
          : (const char*)kroper + trow * 128 + (scb - 256);
      __builtin_amdgcn_global_load_lds((const AS1 void*)src,
          (AS3 void*)(dst + off), 16, 0, 0);
    }
  };
  auto stage_v = [&](int kt0) {                  // 2 VMEM loads / thread
    #pragma unroll
    for (int it = 0; it < 2; ++it) {
      const int off = it * 8192 + wv * 1024;
      const int lb  = off + lane * 16;
      const int row = lb >> 7, cb = lb & 127;
      const int scb = cb ^ ((row & 7) << 4);
      const char* src = (const char*)vTg + ((long)(z * DH + row) * T_ + kt0) * 2 + scb;
      __builtin_amdgcn_global_load_lds((const AS1 void*)src,
          (AS3 void*)(lV + off), 16, 0, 0);
    }
  };

  auto qkt = [&](const char* kb0, f32x4 (&sacc)[4]) {
    __builtin_amdgcn_s_setprio(1);
    #pragma unroll
    for (int kc = 0; kc < 6; ++kc) {
      #pragma unroll
      for (int n = 0; n < 4; ++n) {
        const int krow = n * 16 + rr;
        bf16x8 kb = *(const bf16x8*)(kb0 + krow * 384 +
                                     ((kc * 64 + kq * 16) ^ ((krow & 7) << 4)));
        sacc[n] = __builtin_amdgcn_mfma_f32_16x16x32_bf16(kb, qa[kc], sacc[n], 0, 0, 0);
      }
    }
    __builtin_amdgcn_s_setprio(0);
  };

  float srun = 0.f;

  // ------- pass 1: row sums of exp(s), 3-buffer, stage-after-barrier -------
  stage_k(smem, 0);
  stage_k(smem + 24576, KT);
  for (int kt = 0; kt < NKT; ++kt) {
    if (kt + 1 < NKT) WAITVM(3); else WAITVM(0);
    BARSB();
    if (kt + 2 < NKT) {
      const int nb = (kt + 2) % 3;
      stage_k(smem + nb * 24576, (kt + 2) * KT);   // overwrites buf (kt-1)%3: reads done pre-barrier
    }
    f32x4 sacc[4] = {};
    qkt(smem + (kt % 3) * 24576, sacc);
    float ts = 0.f;
    #pragma unroll
    for (int n = 0; n < 4; ++n)
      #pragma unroll
      for (int r = 0; r < 4; ++r) ts += __expf(sacc[n][r] * scl);
    ts += __shfl_xor(ts, 16);
    ts += __shfl_xor(ts, 32);
    srun += ts;
  }
  const float pis = 1.f / srun;

  // pass-2 prologue: K(0)->@0, V(0)->@49152 (pass-1 WAR-safe pre-barrier)
  stage_k(smem, 0);
  stage_v(0);
  BARSB();                                       // inter-pass

  // ------- pass 2: QK^T, P (LDS now / global late), PV ---------------------
  f32x4 oacc[8] = {};
  const int prow = wv * 16 + rr;
  int cur = 0;
  for (int kt = 0; kt < NKT; ++kt) {
    // queue at this point: K(kt)x3, V(kt)x2, P-stores(kt-1)x4 (newest)
    if (kt == 0) WAITVM(0); else WAITVM(4);
    BARSB();                                     // B0: K(kt), V(kt) ready
    if (kt + 1 < NKT)
      stage_k(smem + (cur ? 0 : 24576), (kt + 1) * KT);  // K(kt-1) reads done pre-B0
    const char* lK = smem + (cur ? 24576 : 0);
    f32x4 sacc[4] = {};
    qkt(lK, sacc);
    const int kt0 = kt * KT;
    f32x4 pv[4];
    #pragma unroll
    for (int n = 0; n < 4; ++n) {
      #pragma unroll
      for (int r = 0; r < 4; ++r) pv[n][r] = __expf(sacc[n][r] * scl) * pis;
      u32x2 pw; pw[0] = pk2(pv[n][0], pv[n][1]); pw[1] = pk2(pv[n][2], pv[n][3]);
      *(u32x2*)(lP + prow * 128 + ((n * 32 + kq * 8) ^ ((prow & 7) << 4))) = pw;
    }
    bf16x8 pa[2];
    #pragma unroll
    for (int kc = 0; kc < 2; ++kc)
      pa[kc] = *(const bf16x8*)(lP + prow * 128 + ((kc * 64 + kq * 16) ^ ((prow & 7) << 4)));
    __builtin_amdgcn_s_setprio(1);
    #pragma unroll
    for (int kc = 0; kc < 2; ++kc) {
      #pragma unroll
      for (int n = 0; n < 8; ++n) {
        const int vrow = n * 16 + rr;
        bf16x8 vb = *(const bf16x8*)(lV + vrow * 128 + ((kc * 64 + kq * 16) ^ ((vrow & 7) << 4)));
        oacc[n] = __builtin_amdgcn_mfma_f32_16x16x32_bf16(pa[kc], vb, oacc[n], 0, 0, 0);
      }
    }
    __builtin_amdgcn_s_setprio(0);
    BARSB();                                     // B2: all waves done with V(kt)
    if (kt + 1 < NKT) stage_v((kt + 1) * KT);
    // P-stores issued LAST -> next tile's wait leaves them riding (vmcnt(4))
    #pragma unroll
    for (int n = 0; n < 4; ++n)
      __builtin_nontemporal_store(pv[n],
          (f32x4*)(patt + ((long)z * T_ + q0 + prow) * T_ + kt0 + n * 16 + kq * 4));
    cur ^= 1;
  }

  #pragma unroll
  for (int n = 0; n < 8; ++n) {
    #pragma unroll
    for (int r = 0; r < 4; ++r) {
      const int q = q0 + wv * 16 + kq * 4 + r;
      xplain[((long)(b * T_ + q)) * DM + h * DH + n * 16 + rr] = __float2bfloat16(oacc[n][r]);
    }
  }
}

// ---------------- Host-side orchestration ----------------
extern "C" void kernel_launch(void* const* d_in, const int* in_sizes, int n_in,
                              void* d_out, int out_size, void* d_ws, size_t ws_size,
                              hipStream_t stream) {
  const float* query = (const float*)d_in[0];
  const float* key   = (const float*)d_in[1];
  const float* W_DKV = (const float*)d_in[3];
  const float* W_UK  = (const float*)d_in[4];
  const float* W_UV  = (const float*)d_in[5];
  const float* W_Q   = (const float*)d_in[6];
  const float* W_KR  = (const float*)d_in[7];
  const float* W_QR  = (const float*)d_in[8];
  const float* W_O   = (const float*)d_in[9];

  float* out  = (float*)d_out;
  float* patt = out + (long)BT * DM;

  char* w = (char*)d_ws;
  auto alloc = [&](size_t bytes) { char* p = w; w += (bytes + 255) & ~(size_t)255; return p; };
  __hip_bfloat16* qB     = (__hip_bfloat16*)alloc((size_t)BT * DM * 2);
  __hip_bfloat16* kB     = (__hip_bfloat16*)alloc((size_t)BT * DM * 2);
  __hip_bfloat16* Wtqall = (__hip_bfloat16*)alloc((size_t)3072 * DM * 2);
  __hip_bfloat16* Wtkall = (__hip_bfloat16*)alloc((size_t)768 * DM * 2);
  __hip_bfloat16* Wtkvup = (__hip_bfloat16*)alloc((size_t)4096 * DC * 2);
  __hip_bfloat16* WtO    = (__hip_bfloat16*)alloc((size_t)DM * DM * 2);
  __hip_bfloat16* q_all  = (__hip_bfloat16*)alloc((size_t)BT * 3072 * 2);
  __hip_bfloat16* ckv    = (__hip_bfloat16*)alloc((size_t)BT * 512 * 2);
  __hip_bfloat16* kroper = (__hip_bfloat16*)alloc((size_t)BT * 64 * 2);
  __hip_bfloat16* knope  = (__hip_bfloat16*)alloc((size_t)BT * 2048 * 2);
  __hip_bfloat16* vT     = (__hip_bfloat16*)alloc((size_t)ZBH * DH * T_ * 2);
  __hip_bfloat16* xplain = (__hip_bfloat16*)alloc((size_t)BT * DM * 2);
  float*          ctab   = (float*)alloc((size_t)T_ * 32 * 4);
  float*          stab   = (float*)alloc((size_t)T_ * 32 * 4);

  // 1) fused prep
  prep<<<dim3(17984), 256, 0, stream>>>(
      query, key, W_Q, W_QR, W_DKV, W_KR, W_UK, W_UV, W_O,
      qB, kB, Wtqall, Wtkall, Wtkvup, WtO, ctab, stab);

  // 2) merged q_all + k_all
  proj_qk<<<dim3(480), 256, 0, stream>>>(
      qB, kB, Wtqall, Wtkall, q_all, ckv, kroper, ctab, stab);

  // 3) kvup = ckv @ [W_UK | W_UV]
  gemm_4w<4><<<dim3(512), 256, 0, stream>>>(
      ckv, Wtkvup, knope, vT, BT, 4096, DC, 512, nullptr, nullptr);

  // 4) fused attention (2 blocks/CU; stores ride the vmcnt queue)
  fused_attn<<<dim3(512), 512, 0, stream>>>(
      q_all, knope, kroper, vT, patt, xplain);

  // 5) output = x @ W_O -> d_out fp32
  gemm_8w_out<<<dim3(256), 512, 0, stream>>>(
      xplain, WtO, out, BT, DM, DM, DM);
}

// Round 15
// 384.334 us; speedup vs baseline: 1.0148x; 1.0148x over previous
//
#include <hip/hip_runtime.h>
#include <hip/hip_bf16.h>
#include <math.h>

// ---------------- Problem constants ----------------
constexpr int B_   = 2;
constexpr int T_   = 2048;
constexpr int DM   = 2048;   // d_model
constexpr int H_   = 16;
constexpr int DH   = 128;    // d_head
constexpr int DC   = 512;    // d_c
constexpr int DR   = 64;     // d_rope
constexpr int DQK  = DH + DR;        // 192
constexpr int BT   = B_ * T_;        // 4096
constexpr int ZBH  = B_ * H_;        // 32

typedef __bf16 bf16x8 __attribute__((ext_vector_type(8)));
typedef float  f32x4  __attribute__((ext_vector_type(4)));
typedef unsigned int u32x2 __attribute__((ext_vector_type(2)));
typedef unsigned short u16x4 __attribute__((ext_vector_type(4)));

__device__ __forceinline__ unsigned pk2(float a, float b) {
  __hip_bfloat162 t = __float22bfloat162_rn(make_float2(a, b));
  return *reinterpret_cast<unsigned*>(&t);
}
__device__ __forceinline__ unsigned short bfbits(float v) {
  __hip_bfloat16 t = __float2bfloat16(v);
  return *reinterpret_cast<unsigned short*>(&t);
}

#define WAITVM(N)   asm volatile("s_waitcnt vmcnt(" #N ")" ::: "memory")
#define BARSB() do { __builtin_amdgcn_s_barrier(); __builtin_amdgcn_sched_barrier(0); } while (0)
#define AS1 __attribute__((address_space(1)))
#define AS3 __attribute__((address_space(3)))

// ---------------- prep: casts + weight transposes + pad + rope tables ------
__global__ __launch_bounds__(256)
void prep(const float* __restrict__ query, const float* __restrict__ key,
          const float* __restrict__ W_Q, const float* __restrict__ W_QR,
          const float* __restrict__ W_DKV, const float* __restrict__ W_KR,
          const float* __restrict__ W_UK, const float* __restrict__ W_UV,
          const float* __restrict__ W_O,
          __hip_bfloat16* __restrict__ qB, __hip_bfloat16* __restrict__ kB,
          __hip_bfloat16* __restrict__ Wtqall, __hip_bfloat16* __restrict__ Wtkall,
          __hip_bfloat16* __restrict__ Wtkvup, __hip_bfloat16* __restrict__ WtO,
          float* __restrict__ ctab, float* __restrict__ stab) {
  __shared__ float tile[32][33];
  const int blk = blockIdx.x;
  const int tid = threadIdx.x;

  if (blk < 4096) {                      // casts: 4096 floats per block
    const float* src = (blk < 2048) ? query : key;
    __hip_bfloat16* dst = (blk < 2048) ? qB : kB;
    const long base = (long)(blk & 2047) * 4096;
    #pragma unroll
    for (int c = 0; c < 4; ++c) {
      const long off = base + c * 1024 + tid * 4;
      float4 f = *(const float4*)(src + off);
      u16x4 pk;
      pk[0] = bfbits(f.x); pk[1] = bfbits(f.y); pk[2] = bfbits(f.z); pk[3] = bfbits(f.w);
      *(u16x4*)(dst + off) = pk;
    }
    return;
  }

  int b = blk - 4096;
  const float* W = nullptr; __hip_bfloat16* Wt = nullptr; int K = 2048, N = 2048;
  if (b < 4096)               { W = W_Q;   Wt = Wtqall; }
  else if ((b -= 4096) < 2048){ W = W_QR;  Wt = Wtqall + (size_t)2048 * 2048; N = 1024; }
  else if ((b -= 2048) < 1024){ W = W_DKV; Wt = Wtkall; N = 512; }
  else if ((b -= 1024) < 128) { W = W_KR;  Wt = Wtkall + (size_t)512 * 2048; N = 64; }
  else if ((b -= 128) < 1024) { W = W_UK;  Wt = Wtkvup; K = 512; }
  else if ((b -= 1024) < 1024){ W = W_UV;  Wt = Wtkvup + (size_t)2048 * 512; K = 512; }
  else if ((b -= 1024) < 4096){ W = W_O;   Wt = WtO; }
  else if ((b -= 4096) < 192) {           // zero-pad Wtkall rows 576..767
    float4 z = {0.f, 0.f, 0.f, 0.f};
    *(float4*)((char*)(Wtkall + (size_t)(576 + b) * 2048) + tid * 16) = z;
    return;
  }
  else {                                  // rope tables
    b -= 192;
    const int i = b * 256 + tid;
    const int t = i >> 5, j = i & 31;
    double inv = pow(10000.0, -(double)j / 32.0);
    double ang = (double)t * inv;
    ctab[i] = (float)cos(ang);
    stab[i] = (float)sin(ang);
    return;
  }
  const int nx = N >> 5;
  const int n0 = (b % nx) << 5, k0 = (b / nx) << 5;
  const int tx = tid & 31, ty = tid >> 5;
  for (int i = ty; i < 32; i += 8)
    tile[i][tx] = W[(long)(k0 + i) * N + n0 + tx];
  __syncthreads();
  for (int i = ty; i < 32; i += 8)
    Wt[(long)(n0 + i) * K + k0 + tx] = __float2bfloat16(tile[tx][i]);
}

// ---------------- 4-wave 128x256 GEMM core (per-wave 128x64, LDS-lean) -----
template <int MODE>
__device__ __forceinline__
void gemm4w_core(const __hip_bfloat16* __restrict__ A, const __hip_bfloat16* __restrict__ Bt,
                 void* __restrict__ C0, void* __restrict__ C1,
                 int N, int K, int lda,
                 const float* __restrict__ ctab, const float* __restrict__ stab,
                 int bid, int nwg, char* lds) {
  const int gnx = N >> 8;
  const int cpx = nwg >> 3;                      // nwg % 8 == 0 for all callers
  const int swz = (bid & 7) * cpx + (bid >> 3);  // bijective XCD chunking
  const int n0 = (swz % gnx) << 8;
  const int m0 = (swz / gnx) << 7;

  const int tid  = threadIdx.x;
  const int wc   = tid >> 6;       // wave = N quarter (0..3)
  const int lane = tid & 63;
  const int rr   = lane & 15;
  const int kq   = lane >> 4;

  const int cs16 = (((tid & 3) ^ ((tid >> 3) & 3)) << 4);
  const int srow = tid >> 2;

  auto stage = [&](int buf, int k0) {            // 6 global_load_lds / thread
    char* base = lds + buf * 24576;
    #pragma unroll
    for (int c = 0; c < 2; ++c) {
      const char* src = (const char*)A + (((long)(m0 + c * 64 + srow)) * lda + k0) * 2 + cs16;
      __builtin_amdgcn_global_load_lds((const AS1 void*)src,
          (AS3 void*)(base + c * 4096 + tid * 16), 16, 0, 0);
    }
    #pragma unroll
    for (int c = 0; c < 4; ++c) {
      const char* src = (const char*)Bt + (((long)(n0 + c * 64 + srow)) * K + k0) * 2 + cs16;
      __builtin_amdgcn_global_load_lds((const AS1 void*)src,
          (AS3 void*)(base + 8192 + c * 4096 + tid * 16), 16, 0, 0);
    }
  };

  const int g16 = ((kq ^ ((rr >> 1) & 3)) << 4);
  const int aoff0 = rr * 64 + g16;                        // + mf*1024
  const int boff0 = 8192 + (wc * 64 + rr) * 64 + g16;     // + nf*1024

  f32x4 acc[8][4] = {};

  auto phase = [&](int buf) {
    char* base = lds + buf * 24576;
    bf16x8 a[8], b[4];
    #pragma unroll
    for (int mf = 0; mf < 8; ++mf) a[mf] = *(const bf16x8*)(base + aoff0 + mf * 1024);
    #pragma unroll
    for (int nf = 0; nf < 4; ++nf) b[nf] = *(const bf16x8*)(base + boff0 + nf * 1024);
    __builtin_amdgcn_s_setprio(1);
    #pragma unroll
    for (int mf = 0; mf < 8; ++mf)
      #pragma unroll
      for (int nf = 0; nf < 4; ++nf)
        acc[mf][nf] = __builtin_amdgcn_mfma_f32_16x16x32_bf16(a[mf], b[nf], acc[mf][nf], 0, 0, 0);
    __builtin_amdgcn_s_setprio(0);
  };

  const int NT = K >> 5;                         // K-32 tiles
  stage(0, 0); stage(1, 32);                     // 12 loads in flight
  int cur = 0;
  for (int t = 0; t < NT; ++t) {
    if (t + 1 < NT) WAITVM(6); else WAITVM(0);
    BARSB();
    if (t + 2 < NT) {
      const int b2 = (cur + 2 >= 3) ? cur - 1 : cur + 2;
      stage(b2, (t + 2) << 5);
    }
    phase(cur);
    cur = (cur + 1 >= 3) ? 0 : cur + 1;
  }

  // epilogue: row = m0 + mf*16 + kq*4 + j, col = n0 + wc*64 + nf*16 + rr
  #pragma unroll
  for (int mf = 0; mf < 8; ++mf) {
    #pragma unroll
    for (int nf = 0; nf < 4; ++nf) {
      const int col = n0 + wc * 64 + nf * 16 + rr;
      const int rbase = m0 + mf * 16 + kq * 4;
      if constexpr (MODE == 1) {
        float* C = (float*)C0;
        #pragma unroll
        for (int j = 0; j < 4; ++j)
          __builtin_nontemporal_store(acc[mf][nf][j], &C[(long)(rbase + j) * N + col]);
      } else if constexpr (MODE == 2) {
        __hip_bfloat16* qall = (__hip_bfloat16*)C0;
        if (col < 2048) {
          #pragma unroll
          for (int j = 0; j < 4; ++j)
            qall[(long)(rbase + j) * 3072 + col] = __float2bfloat16(acc[mf][nf][j]);
        } else {
          const int dr = (col - 2048) & 63;
          const int jj = dr >> 1;
          #pragma unroll
          for (int j = 0; j < 4; ++j) {
            const int row = rbase + j;
            const int t = row & (T_ - 1);
            const float c = ctab[t * 32 + jj], s = stab[t * 32 + jj];
            const float v  = acc[mf][nf][j];
            const float pv = __shfl_xor(v, 1);
            const float res = (dr & 1) ? (pv * s + v * c) : (v * c - pv * s);
            qall[(long)row * 3072 + col] = __float2bfloat16(res);
          }
        }
      } else if constexpr (MODE == 3) {
        __hip_bfloat16* ckv = (__hip_bfloat16*)C0;
        __hip_bfloat16* krp = (__hip_bfloat16*)C1;
        if (col < 512) {
          #pragma unroll
          for (int j = 0; j < 4; ++j)
            ckv[(long)(rbase + j) * 512 + col] = __float2bfloat16(acc[mf][nf][j]);
        } else if (col < 576) {
          const int dr = col - 512;
          const int jj = dr >> 1;
          #pragma unroll
          for (int j = 0; j < 4; ++j) {
            const int row = rbase + j;
            const int t = row & (T_ - 1);
            const float c = ctab[t * 32 + jj], s = stab[t * 32 + jj];
            const float v  = acc[mf][nf][j];
            const float pv = __shfl_xor(v, 1);
            const float res = (dr & 1) ? (pv * s + v * c) : (v * c - pv * s);
            krp[(long)row * 64 + dr] = __float2bfloat16(res);
          }
        }            // cols >= 576: zero-padded, discard
      } else if constexpr (MODE == 4) {
        __hip_bfloat16* knope = (__hip_bfloat16*)C0;
        __hip_bfloat16* vT    = (__hip_bfloat16*)C1;
        if (col < 2048) {
          #pragma unroll
          for (int j = 0; j < 4; ++j)
            knope[(long)(rbase + j) * 2048 + col] = __float2bfloat16(acc[mf][nf][j]);
        } else {
          const int h = (col - 2048) >> 7, d = (col - 2048) & 127;
          const int z = (rbase >> 11) * 16 + h;
          const int t0 = rbase & (T_ - 1);
          u16x4 pk;
          #pragma unroll
          for (int j = 0; j < 4; ++j) pk[j] = bfbits(acc[mf][nf][j]);
          *(u16x4*)((__hip_bfloat16*)vT + ((long)z * DH + d) * T_ + t0) = pk;
        }
      }
    }
  }
}

template <int MODE>
__global__ __launch_bounds__(256, 2)
void gemm_4w(const __hip_bfloat16* __restrict__ A, const __hip_bfloat16* __restrict__ Bt,
             void* __restrict__ C0, void* __restrict__ C1,
             int M, int N, int K, int lda,
             const float* __restrict__ ctab, const float* __restrict__ stab) {
  __shared__ __align__(16) char lds[73728];
  gemm4w_core<MODE>(A, Bt, C0, C1, N, K, lda, ctab, stab,
                    blockIdx.x, (M >> 7) * (N >> 8), lds);
}

// ---- merged q_all + k_all projection: independent GEMMs, one dispatch -----
__global__ __launch_bounds__(256, 2)
void proj_qk(const __hip_bfloat16* __restrict__ qB, const __hip_bfloat16* __restrict__ kB,
             const __hip_bfloat16* __restrict__ Wtqall, const __hip_bfloat16* __restrict__ Wtkall,
             __hip_bfloat16* __restrict__ q_all, __hip_bfloat16* __restrict__ ckv,
             __hip_bfloat16* __restrict__ kroper,
             const float* __restrict__ ctab, const float* __restrict__ stab) {
  __shared__ __align__(16) char lds[73728];
  if (blockIdx.x < 384)
    gemm4w_core<2>(qB, Wtqall, q_all, nullptr, 3072, 2048, 2048, ctab, stab,
                   blockIdx.x, 384, lds);
  else
    gemm4w_core<3>(kB, Wtkall, ckv, kroper, 768, 2048, 2048, ctab, stab,
                   blockIdx.x - 384, 96, lds);
}

// ---------------- 8-wave 128x256 GEMM (out-GEMM: 8 waves/CU at grid 256) ---
__global__ __launch_bounds__(512, 2)
void gemm_8w_out(const __hip_bfloat16* __restrict__ A, const __hip_bfloat16* __restrict__ Bt,
                 float* __restrict__ C, int M, int N, int K, int lda) {
  const int gnx = N >> 8;
  const int nwg = (M >> 7) * gnx;
  const int cpx = nwg >> 3;
  const int bid = blockIdx.x;
  const int swz = (bid & 7) * cpx + (bid >> 3);
  const int n0 = (swz % gnx) << 8;
  const int m0 = (swz / gnx) << 7;

  __shared__ __align__(16) char lds[147456];

  const int tid  = threadIdx.x;
  const int wv   = tid >> 6;
  const int lane = tid & 63;
  const int wr   = wv >> 2;
  const int wc   = wv & 3;
  const int rr   = lane & 15;
  const int kq   = lane >> 4;

  const int cs16 = (((tid & 3) ^ ((tid >> 3) & 3)) << 4);
  const long arow  = m0 + (tid >> 2);
  const long brow0 = n0 + (tid >> 2);
  const long brow1 = n0 + 128 + (tid >> 2);

  auto stage = [&](int buf, int kh, int k0) {
    char* base = lds + buf * 49152 + kh * 24576;
    const long kk = (long)k0 + kh * 32;
    const char* asrc = (const char*)A + (arow * lda + kk) * 2 + cs16;
    __builtin_amdgcn_global_load_lds((const AS1 void*)asrc,
                                     (AS3 void*)(base + tid * 16), 16, 0, 0);
    const char* bsrc0 = (const char*)Bt + (brow0 * K + kk) * 2 + cs16;
    __builtin_amdgcn_global_load_lds((const AS1 void*)bsrc0,
                                     (AS3 void*)(base + 8192 + tid * 16), 16, 0, 0);
    const char* bsrc1 = (const char*)Bt + (brow1 * K + kk) * 2 + cs16;
    __builtin_amdgcn_global_load_lds((const AS1 void*)bsrc1,
                                     (AS3 void*)(base + 16384 + tid * 16), 16, 0, 0);
  };

  const int g16 = ((kq ^ ((rr >> 1) & 3)) << 4);
  const int aoff0 = (wr * 64 + rr) * 64 + g16;
  const int boff0 = 8192 + (wc * 64 + rr) * 64 + g16;

  f32x4 acc[4][4] = {};

  auto phase = [&](int buf, int kh) {
    char* base = lds + buf * 49152 + kh * 24576;
    bf16x8 a[4], b[4];
    #pragma unroll
    for (int mf = 0; mf < 4; ++mf) a[mf] = *(const bf16x8*)(base + aoff0 + mf * 1024);
    #pragma unroll
    for (int nf = 0; nf < 4; ++nf) b[nf] = *(const bf16x8*)(base + boff0 + nf * 1024);
    __builtin_amdgcn_s_setprio(1);
    #pragma unroll
    for (int mf = 0; mf < 4; ++mf)
      #pragma unroll
      for (int nf = 0; nf < 4; ++nf)
        acc[mf][nf] = __builtin_amdgcn_mfma_f32_16x16x32_bf16(a[mf], b[nf], acc[mf][nf], 0, 0, 0);
    __builtin_amdgcn_s_setprio(0);
  };

  const int NT = K >> 6;
  stage(0, 0, 0); stage(0, 1, 0);
  stage(1, 0, 64); stage(1, 1, 64);
  int cur = 0;
  for (int t = 0; t < NT; ++t) {
    const int b2 = (cur + 2 >= 3) ? cur - 1 : cur + 2;
    if (t + 2 < NT) {
      const int k2 = (t + 2) << 6;
      WAITVM(9);  BARSB();
      stage(b2, 0, k2);
      phase(cur, 0);
      WAITVM(9);  BARSB();
      stage(b2, 1, k2);
      phase(cur, 1);
    } else if (t + 2 == NT) {
      WAITVM(9);  BARSB();  phase(cur, 0);
      WAITVM(6);  BARSB();  phase(cur, 1);
    } else {
      WAITVM(3);  BARSB();  phase(cur, 0);
      WAITVM(0);  BARSB();  phase(cur, 1);
    }
    cur = (cur + 1 >= 3) ? 0 : cur + 1;
  }

  #pragma unroll
  for (int mf = 0; mf < 4; ++mf) {
    #pragma unroll
    for (int nf = 0; nf < 4; ++nf) {
      const int col = n0 + wc * 64 + nf * 16 + rr;
      const int rbase = m0 + wr * 64 + mf * 16 + kq * 4;
      #pragma unroll
      for (int j = 0; j < 4; ++j)
        __builtin_nontemporal_store(acc[mf][nf][j], &C[(long)(rbase + j) * N + col]);
    }
  }
}

// ---------------- Fused attention: scores + softmax + PV -------------------
// 80 KB LDS -> 2 blocks/CU co-resident: one block's MFMA-bound pass 1 hides
// the other's HBM-write-bound pass 2 (537 MB P-store floor).
// Pass 1: 3 K-buffers, 2-ahead, stage-after-barrier, 1 barrier/tile.
// Pass 2: K dbuf + single V + P; 2 barriers/tile (B0 inputs-ready, B2 V-free).
__global__ __launch_bounds__(512, 4)
void fused_attn(const __hip_bfloat16* __restrict__ q_all,
                const __hip_bfloat16* __restrict__ knope,
                const __hip_bfloat16* __restrict__ kroper,
                const __hip_bfloat16* __restrict__ vTg,
                float* __restrict__ patt,
                __hip_bfloat16* __restrict__ xplain) {
  constexpr int KT = 64;
  constexpr int NKT = T_ / KT;           // 32
  const int bid = blockIdx.x;
  const int swz = (bid & 7) * 64 + (bid >> 3);
  const int z  = swz >> 4;
  const int q0 = (swz & 15) << 7;
  const int b  = z >> 4, h = z & 15;
  const int tid  = threadIdx.x;
  const int wv   = tid >> 6;
  const int lane = tid & 63;
  const int rr   = lane & 15;
  const int kq   = lane >> 4;
  const float scl = 0.0721687836487032f; // 1/sqrt(192)

  // map: pass1 K bufs @0/24576/49152 ; pass2 K0@0 K1@24576 V@49152 P@65536
  __shared__ __align__(16) char smem[81920];
  char* const lV = smem + 49152;
  char* const lP = smem + 65536;

  const long qrow = (long)(b * T_) + q0 + wv * 16 + rr;
  const __hip_bfloat16* qn = q_all + qrow * 3072 + h * 128;
  const __hip_bfloat16* qr = q_all + qrow * 3072 + 2048 + h * 64;
  bf16x8 qa[6];
  #pragma unroll
  for (int kc = 0; kc < 4; ++kc) qa[kc] = *(const bf16x8*)(qn + kc * 32 + kq * 8);
  #pragma unroll
  for (int kc = 0; kc < 2; ++kc) qa[4 + kc] = *(const bf16x8*)(qr + kc * 32 + kq * 8);

  auto stage_k = [&](char* dst, int kt0) {       // 3 VMEM loads / thread
    #pragma unroll
    for (int it = 0; it < 3; ++it) {
      const int off = it * 8192 + wv * 1024;
      const int lb  = off + lane * 16;
      const int row = lb / 384, cb = lb % 384;
      const int scb = cb ^ ((row & 7) << 4);
      const long trow = (long)(b * T_) + kt0 + row;
      const char* src = (scb < 256)
          ? (const char*)knope + trow * 4096 + h * 256 + scb
          : (const char*)kroper + trow * 128 + (scb - 256);
      __builtin_amdgcn_global_load_lds((const AS1 void*)src,
          (AS3 void*)(dst + off), 16, 0, 0);
    }
  };
  auto stage_v = [&](int kt0) {                  // 2 VMEM loads / thread
    #pragma unroll
    for (int it = 0; it < 2; ++it) {
      const int off = it * 8192 + wv * 1024;
      const int lb  = off + lane * 16;
      const int row = lb >> 7, cb = lb & 127;
      const int scb = cb ^ ((row & 7) << 4);
      const char* src = (const char*)vTg + ((long)(z * DH + row) * T_ + kt0) * 2 + scb;
      __builtin_amdgcn_global_load_lds((const AS1 void*)src,
          (AS3 void*)(lV + off), 16, 0, 0);
    }
  };

  auto qkt = [&](const char* kb0, f32x4 (&sacc)[4]) {
    __builtin_amdgcn_s_setprio(1);
    #pragma unroll
    for (int kc = 0; kc < 6; ++kc) {
      #pragma unroll
      for (int n = 0; n < 4; ++n) {
        const int krow = n * 16 + rr;
        bf16x8 kb = *(const bf16x8*)(kb0 + krow * 384 +
                                     ((kc * 64 + kq * 16) ^ ((krow & 7) << 4)));
        sacc[n] = __builtin_amdgcn_mfma_f32_16x16x32_bf16(kb, qa[kc], sacc[n], 0, 0, 0);
      }
    }
    __builtin_amdgcn_s_setprio(0);
  };

  float srun = 0.f;

  // ------- pass 1: row sums of exp(s), 3-buffer, stage-after-barrier -------
  stage_k(smem, 0);
  stage_k(smem + 24576, KT);
  for (int kt = 0; kt < NKT; ++kt) {
    if (kt + 1 < NKT) WAITVM(3); else WAITVM(0);
    BARSB();
    if (kt + 2 < NKT) {
      const int nb = (kt + 2) % 3;
      stage_k(smem + nb * 24576, (kt + 2) * KT);   // overwrites buf (kt-1)%3: reads done pre-barrier
    }
    f32x4 sacc[4] = {};
    qkt(smem + (kt % 3) * 24576, sacc);
    float ts = 0.f;
    #pragma unroll
    for (int n = 0; n < 4; ++n)
      #pragma unroll
      for (int r = 0; r < 4; ++r) ts += __expf(sacc[n][r] * scl);
    ts += __shfl_xor(ts, 16);
    ts += __shfl_xor(ts, 32);
    srun += ts;
  }
  const float pis = 1.f / srun;

  // pass-2 prologue: K(0)->@0 (pass-1 buf0, reads ended iter 30), V(0)->@49152
  // (pass-1 buf2, reads ended iter 29) -- both WAR-safe pre-barrier.
  stage_k(smem, 0);
  stage_v(0);
  BARSB();                                       // inter-pass

  // ------- pass 2: recompute S, write P, PV (2 barriers/tile) --------------
  f32x4 oacc[8] = {};
  const int prow = wv * 16 + rr;
  int cur = 0;
  for (int kt = 0; kt < NKT; ++kt) {
    WAITVM(0);                                   // K(kt), V(kt) landed (V newest)
    BARSB();                                     // B0: inputs ready
    if (kt + 1 < NKT)
      stage_k(smem + (cur ? 0 : 24576), (kt + 1) * KT);  // K(kt-1) reads done pre-B0
    const char* lK = smem + (cur ? 24576 : 0);
    f32x4 sacc[4] = {};
    qkt(lK, sacc);
    const int kt0 = kt * KT;
    #pragma unroll
    for (int n = 0; n < 4; ++n) {
      f32x4 pv;
      #pragma unroll
      for (int r = 0; r < 4; ++r) pv[r] = __expf(sacc[n][r] * scl) * pis;
      __builtin_nontemporal_store(pv,
          (f32x4*)(patt + ((long)z * T_ + q0 + prow) * T_ + kt0 + n * 16 + kq * 4));
      u32x2 pw; pw[0] = pk2(pv[0], pv[1]); pw[1] = pk2(pv[2], pv[3]);
      *(u32x2*)(lP + prow * 128 + ((n * 32 + kq * 8) ^ ((prow & 7) << 4))) = pw;
    }
    bf16x8 pa[2];
    #pragma unroll
    for (int kc = 0; kc < 2; ++kc)
      pa[kc] = *(const bf16x8*)(lP + prow * 128 + ((kc * 64 + kq * 16) ^ ((prow & 7) << 4)));
    __builtin_amdgcn_s_setprio(1);
    #pragma unroll
    for (int kc = 0; kc < 2; ++kc) {
      #pragma unroll
      for (int n = 0; n < 8; ++n) {
        const int vrow = n * 16 + rr;
        bf16x8 vb = *(const bf16x8*)(lV + vrow * 128 + ((kc * 64 + kq * 16) ^ ((vrow & 7) << 4)));
        oacc[n] = __builtin_amdgcn_mfma_f32_16x16x32_bf16(pa[kc], vb, oacc[n], 0, 0, 0);
      }
    }
    __builtin_amdgcn_s_setprio(0);
    BARSB();                                     // B2: all waves done with V(kt)
    if (kt + 1 < NKT) stage_v((kt + 1) * KT);
    cur ^= 1;
  }

  #pragma unroll
  for (int n = 0; n < 8; ++n) {
    #pragma unroll
    for (int r = 0; r < 4; ++r) {
      const int q = q0 + wv * 16 + kq * 4 + r;
      xplain[((long)(b * T_ + q)) * DM + h * DH + n * 16 + rr] = __float2bfloat16(oacc[n][r]);
    }
  }
}

// ---------------- Host-side orchestration ----------------
extern "C" void kernel_launch(void* const* d_in, const int* in_sizes, int n_in,
                              void* d_out, int out_size, void* d_ws, size_t ws_size,
                              hipStream_t stream) {
  const float* query = (const float*)d_in[0];
  const float* key   = (const float*)d_in[1];
  const float* W_DKV = (const float*)d_in[3];
  const float* W_UK  = (const float*)d_in[4];
  const float* W_UV  = (const float*)d_in[5];
  const float* W_Q   = (const float*)d_in[6];
  const float* W_KR  = (const float*)d_in[7];
  const float* W_QR  = (const float*)d_in[8];
  const float* W_O   = (const float*)d_in[9];

  float* out  = (float*)d_out;
  float* patt = out + (long)BT * DM;

  char* w = (char*)d_ws;
  auto alloc = [&](size_t bytes) { char* p = w; w += (bytes + 255) & ~(size_t)255; return p; };
  __hip_bfloat16* qB     = (__hip_bfloat16*)alloc((size_t)BT * DM * 2);
  __hip_bfloat16* kB     = (__hip_bfloat16*)alloc((size_t)BT * DM * 2);
  __hip_bfloat16* Wtqall = (__hip_bfloat16*)alloc((size_t)3072 * DM * 2);
  __hip_bfloat16* Wtkall = (__hip_bfloat16*)alloc((size_t)768 * DM * 2);
  __hip_bfloat16* Wtkvup = (__hip_bfloat16*)alloc((size_t)4096 * DC * 2);
  __hip_bfloat16* WtO    = (__hip_bfloat16*)alloc((size_t)DM * DM * 2);
  __hip_bfloat16* q_all  = (__hip_bfloat16*)alloc((size_t)BT * 3072 * 2);
  __hip_bfloat16* ckv    = (__hip_bfloat16*)alloc((size_t)BT * 512 * 2);
  __hip_bfloat16* kroper = (__hip_bfloat16*)alloc((size_t)BT * 64 * 2);
  __hip_bfloat16* knope  = (__hip_bfloat16*)alloc((size_t)BT * 2048 * 2);
  __hip_bfloat16* vT     = (__hip_bfloat16*)alloc((size_t)ZBH * DH * T_ * 2);
  __hip_bfloat16* xplain = (__hip_bfloat16*)alloc((size_t)BT * DM * 2);
  float*          ctab   = (float*)alloc((size_t)T_ * 32 * 4);
  float*          stab   = (float*)alloc((size_t)T_ * 32 * 4);

  // 1) fused prep
  prep<<<dim3(17984), 256, 0, stream>>>(
      query, key, W_Q, W_QR, W_DKV, W_KR, W_UK, W_UV, W_O,
      qB, kB, Wtqall, Wtkall, Wtkvup, WtO, ctab, stab);

  // 2) merged q_all + k_all
  proj_qk<<<dim3(480), 256, 0, stream>>>(
      qB, kB, Wtqall, Wtkall, q_all, ckv, kroper, ctab, stab);

  // 3) kvup = ckv @ [W_UK | W_UV]
  gemm_4w<4><<<dim3(512), 256, 0, stream>>>(
      ckv, Wtkvup, knope, vT, BT, 4096, DC, 512, nullptr, nullptr);

  // 4) fused attention (80 KB LDS -> 2 blocks/CU, fully co-resident grid)
  fused_attn<<<dim3(512), 512, 0, stream>>>(
      q_all, knope, kroper, vT, patt, xplain);

  // 5) output = x @ W_O -> d_out fp32
  gemm_8w_out<<<dim3(256), 512, 0, stream>>>(
      xplain, WtO, out, BT, DM, DM, DM);
}